// Round 19
// baseline (427.004 us; speedup 1.0000x reference)
//
#include <hip/hip_runtime.h>

typedef float f4 __attribute__((ext_vector_type(4)));

#define Nn 256
#define Mm 512
#define Dd 64
#define EPSF 1e-6f
#define INFF 1e30f
#define BC 8
#define PROW (BC + 1)      // payload rows per chunk: 8 cbar + 1 crow row
#define NCHUNK (Nn / BC)   // 32
#define R 16               // rows per wave-stage
#define NBLK 8             // pipeline groups (blocks)
#define WVS 4              // waves per block (256 threads, 1 wave/SIMD -> 512 VGPR cap)
#define SST (NBLK * WVS)   // 32 stages total
#define SLOTS 4            // LDS slice ring depth
#define QSTR 260           // qc row stride (keeps f4 reads 16B-aligned)
#define AUXC 0x11          // CPol: SC0 (bit0) | SC1 (bit4) -> LLC-coherent DMA

// workspace layout (float offsets; all 4-float aligned)
#define OFF_D     0                    // d[m][n]            512*256
#define OFF_QC    131072               // qc[t][n]=q[n][t], stride QSTR (256 rows)
#define OFF_P     197632               // p[257]
#define OFF_WT    197892               // wT[t][n]=w[n][t]   256*256
#define OFF_CBAR  263428               // payload slices [NCHUNK][PROW*Nn] = 73728
#define OFF_FLAG  337156               // flags[blk][chunk], NBLK*NCHUNK ints

// ---------------- LLC-coherent (sc0 sc1) helpers — proven round-2 forms ----------------
__device__ __forceinline__ int llc_load_int(const int* p) {
  int v;
  asm volatile("global_load_dword %0, %1, off sc0 sc1\n\ts_waitcnt vmcnt(0)"
               : "=v"(v) : "v"(p) : "memory");
  return v;
}
__device__ __forceinline__ void llc_store_int(int* p, int v) {
  asm volatile("global_store_dword %0, %1, off sc0 sc1" :: "v"(p), "v"(v) : "memory");
}
__device__ __forceinline__ void llc_store_cbar8(float* b0, const f4 c[8]) {
  float* b1 = b0 + 4 * Nn;
  asm volatile(
    "global_store_dwordx4 %8, %0, off sc0 sc1\n\t"
    "global_store_dwordx4 %8, %1, off offset:1024 sc0 sc1\n\t"
    "global_store_dwordx4 %8, %2, off offset:2048 sc0 sc1\n\t"
    "global_store_dwordx4 %8, %3, off offset:3072 sc0 sc1\n\t"
    "global_store_dwordx4 %9, %4, off sc0 sc1\n\t"
    "global_store_dwordx4 %9, %5, off offset:1024 sc0 sc1\n\t"
    "global_store_dwordx4 %9, %6, off offset:2048 sc0 sc1\n\t"
    "global_store_dwordx4 %9, %7, off offset:3072 sc0 sc1\n\t"
    "s_waitcnt vmcnt(0)"
    :: "v"(c[0]), "v"(c[1]), "v"(c[2]), "v"(c[3]),
       "v"(c[4]), "v"(c[5]), "v"(c[6]), "v"(c[7]),
       "v"(b0), "v"(b1)
    : "memory");
}
__device__ __forceinline__ float rdlane(float v, int l) {
  return __int_as_float(__builtin_amdgcn_readlane(__float_as_int(v), l));
}
// register-less async DMA: 16B/lane global -> LDS (lane i lands at ldst + i*16B)
typedef const __attribute__((address_space(1))) float gfloat;
typedef __attribute__((address_space(3))) float lfloat;
__device__ __forceinline__ void dma16(const float* g, float* l) {
  __builtin_amdgcn_global_load_lds((gfloat*)g, (lfloat*)l, 16, 0, AUXC);
}
// issue PROW async DMA rows for one payload slice (no destination registers)
__device__ __forceinline__ void dma_payload(const float* slice, float* stgbuf, int lane) {
#pragma unroll
  for (int tt = 0; tt < PROW; tt++)
    dma16(slice + tt * Nn + 4 * lane, stgbuf + tt * Nn);
}

// ---- fused setup: dist (b<512) | tiled transpose (b<576) | init (b==576) | reach (b==577) ----
__global__ __launch_bounds__(256) void k_pre(const float* __restrict__ x,
                                             const float* __restrict__ y,
                                             const float* __restrict__ q,
                                             float* __restrict__ ws) {
  __shared__ float xs[Dd];
  __shared__ float tile[32][33];
  __shared__ float p[257];
  __shared__ float vsnap[64];
  __shared__ float qtile[64][65];
  const int b = blockIdx.x, t = threadIdx.x;
  if (b < Mm) {
    if (t < Dd) xs[t] = x[b * Dd + t];
    __syncthreads();
    const float4* y4 = (const float4*)(y + t * Dd);
    float acc = 0.f;
#pragma unroll
    for (int k = 0; k < Dd / 4; k++) {
      float4 v = y4[k];
      float a0 = xs[4*k+0] - v.x, a1 = xs[4*k+1] - v.y;
      float a2 = xs[4*k+2] - v.z, a3 = xs[4*k+3] - v.w;
      acc += a0*a0 + a1*a1 + a2*a2 + a3*a3;
    }
    ws[OFF_D + b * Nn + t] = sqrtf(acc);
  } else if (b < Mm + 64) {
    // tiled 32x32 transpose: qc[t][j] = q[j][t], both sides coalesced
    const int tb = b - Mm;
    const int t0 = (tb & 7) * 32;
    const int j0 = (tb >> 3) * 32;
    const int tx = t & 31, ty = t >> 5;   // 32 x 8
#pragma unroll
    for (int dy = 0; dy < 4; dy++)
      tile[ty + 8 * dy][tx] = q[(j0 + ty + 8 * dy) * Nn + t0 + tx];
    __syncthreads();
#pragma unroll
    for (int dy = 0; dy < 4; dy++)
      ws[OFF_QC + (t0 + ty + 8 * dy) * QSTR + j0 + tx] = tile[tx][ty + 8 * dy];
  } else if (b == Mm + 64) {
    ((int*)(ws + OFF_FLAG))[t] = 0;       // NBLK*NCHUNK == 256 flags
  } else {
    // ---- reachability (round-12 verified code; q read directly) ----
    float* p_out = ws + OFF_P;
    p[t] = (t == 0) ? 1.f : 0.f;
    if (t == 0) p[256] = 0.f;
    __syncthreads();
    for (int g = 0; g < 4; g++) {
      int g0 = g * 64;
      for (int z = 0; z < 16; z++) {
        int idx = t + z * 256, l = idx >> 6, k = idx & 63;
        qtile[k][l] = q[(g0 + l) * Nn + g0 + k];
      }
      __syncthreads();
      if (t < 64) {
        float pv = p[g0 + t];
        for (int k = 0; k < 64; k++) {
          float v = __shfl(pv, k, 64);
          if (t == k) vsnap[k] = v;
          pv += v * qtile[k][t];
        }
      }
      __syncthreads();
      float4 qs[16];
      const float4* qrow = (const float4*)(q + t * Nn + g0);
#pragma unroll
      for (int i = 0; i < 16; i++) qs[i] = qrow[i];
      float acc = p[t];
#pragma unroll
      for (int i = 0; i < 16; i++) {
        acc += vsnap[4*i+0] * qs[i].x;
        acc += vsnap[4*i+1] * qs[i].y;
        acc += vsnap[4*i+2] * qs[i].z;
        acc += vsnap[4*i+3] * qs[i].w;
      }
      float acc2 = 0.f;
      if (t == 0) {
        acc2 = p[256];
        const float4* qlast = (const float4*)(q + 256 * Nn + g0);
#pragma unroll
        for (int i = 0; i < 16; i++) {
          float4 v = qlast[i];
          acc2 += vsnap[4*i+0] * v.x + vsnap[4*i+1] * v.y
                + vsnap[4*i+2] * v.z + vsnap[4*i+3] * v.w;
        }
      }
      __syncthreads();
      p[t] = acc;
      if (t == 0) p[256] = acc2;
      __syncthreads();
    }
    p_out[t] = p[t];
    if (t == 0) p_out[256] = p[256];
  }
}

// wT only — no atomics (k_main sums its own columns in a coalesced prologue)
__global__ __launch_bounds__(256) void k_wbuild(const float* __restrict__ qc, const float* __restrict__ p,
                                                float* __restrict__ wT) {
  int t = blockIdx.x, n = threadIdx.x;
  float v = 0.f;
  if (t < n) v = p[t] * qc[t * QSTR + n] / (p[n] + EPSF);
  wT[t * Nn + n] = v;
}

// ---------------- main systolic DP: 8 blocks x 4 waves, DMA-staged boundary ----------------
// R16 branch-free body unchanged. Boundary change: wave 0 consumes chunk j from an LDS
// staging buffer and prefetches chunk j+1 via REGISTER-LESS global_load_lds DMA (9 rows:
// 8 cbar + 1 crow folded into the payload slice), issued strictly AFTER the completed-flag
// observation (proven R2 ordering). The __syncthreads pre-barrier vmcnt(0) drains the DMA
// before next-step consumption; no destination registers exist -> no allocator hazard.
__global__ __launch_bounds__(256, 1) void k_main(const float* __restrict__ d,
                                                 const float* __restrict__ wT,
                                                 float* __restrict__ cbarG,
                                                 int* __restrict__ flags,
                                                 const float* __restrict__ q,
                                                 const float* __restrict__ p,
                                                 float* __restrict__ out) {
  __shared__ __align__(16) float sbuf[SLOTS][BC * Nn];       // 32 KB slice ring
  __shared__ __align__(16) float stg[2][PROW * Nn];          // 18 KB DMA staging (dbuf)
  __shared__ __align__(16) float crow_lds[WVS][SLOTS][BC];   // crow handoffs
  __shared__ __align__(16) float crow_fin[Nn];               // last block: C_last stash

  const int tid  = threadIdx.x;
  const int wave = tid >> 6;         // 0..3: stage within block
  const int lane = tid & 63;         // owns columns 4*lane .. 4*lane+3
  const int blk  = blockIdx.x;
  const int stage = blk * WVS + wave;
  const int m0 = stage * R;

  f4 dl[R], S[R];
#pragma unroll
  for (int r = 0; r < R; r++) {
    dl[r] = *(const f4*)(d + (m0 + r) * Nn + 4 * lane);
    S[r] = (f4){0.f, 0.f, 0.f, 0.f};
  }
  // Wt prologue: column sums of wT (coalesced; wT is zero where t >= n)
  f4 Wt = (f4){0.f, 0.f, 0.f, 0.f};
#pragma unroll 8
  for (int t = 0; t < Nn; t++)
    Wt += *(const f4*)(wT + t * Nn + 4 * lane);

  // ---- wave-0 prologue: flag-poll chunk 0, then async DMA its payload into stg[0] ----
  if (wave == 0 && blk > 0) {
    const int* fp = flags + (blk - 1) * NCHUNK;
    while (llc_load_int(fp) == 0) __builtin_amdgcn_s_sleep(1);
    dma_payload(cbarG, &stg[0][0], lane);
  }
  __syncthreads();   // pre-barrier vmcnt(0) drains the DMA -> stg[0] valid

#pragma clang loop unroll(disable)
  for (int s = 0; s < NCHUNK + WVS - 1; s++) {
    const int j = s - wave;
    if (j >= 0 && j < NCHUNK) {
      // wT chunk: issue FIRST so the poll's vmcnt(0) lands them for free
      f4 wv[BC];
#pragma unroll
      for (int tt = 0; tt < BC; tt++)
        wv[tt] = *(const f4*)(wT + (j * BC + tt) * Nn + 4 * lane);

      f4 c[BC], cpl, cph;
      float* lsl = &sbuf[j & (SLOTS - 1)][0] + 4 * lane;

      if (wave == 0) {
        if (blk > 0) {
          // consume DMA-staged chunk j
          const float* sb = &stg[j & 1][0];
#pragma unroll
          for (int tt = 0; tt < BC; tt++) c[tt] = *(const f4*)(sb + tt * Nn + 4 * lane);
          cpl = *(const f4*)(sb + BC * Nn);
          cph = *(const f4*)(sb + BC * Nn + 4);
          // prefetch chunk j+1: completed-flag poll, THEN register-less DMA issue
          if (j + 1 < NCHUNK) {
            const int* fp = flags + (blk - 1) * NCHUNK + (j + 1);
            while (llc_load_int(fp) == 0) __builtin_amdgcn_s_sleep(1);
            dma_payload(cbarG + (size_t)(j + 1) * PROW * Nn, &stg[(j + 1) & 1][0], lane);
          }
        } else {
          cpl = (f4){INFF, INFF, INFF, INFF};
          cph = cpl;
#pragma unroll
          for (int tt = 0; tt < BC; tt++) c[tt] = cpl;
        }
      } else {
        // slice written by wave-1 at step s-1 (barrier-separated)
#pragma unroll
        for (int tt = 0; tt < BC; tt++) c[tt] = *(const f4*)(lsl + tt * Nn);
        const float* cr = &crow_lds[wave - 1][j & (SLOTS - 1)][0];
        cpl = *(const f4*)cr;
        cph = *(const f4*)(cr + 4);
      }

      f4 clast4;
      const bool isJ0 = (j == 0);
#pragma unroll
      for (int tt = 0; tt < BC; tt++) {
        const int owner = 2 * j + (tt >> 2);   // wave-uniform
        const int comp = tt & 3;               // == t & 3 (compile-time)
        const bool isT0 = isJ0 && (tt == 0);

        float up = (tt < 4) ? cpl[comp] : cph[comp];   // upstream C[m0-1][t]
        float prcMin = up;                              // for cmin2
        float prcVal = up;                              // for the t==0 value chain
        if (isT0 && stage == 0) prcVal = 0.f;
        float cml[R];
#pragma unroll
        for (int r = 0; r < R; r++) {
          float Cv;
          if (isT0) Cv = dl[r][0] + prcVal;                       // C[m][0] = d + C[m-1][0]
          else      Cv = fmaf(dl[r][comp], Wt[comp], S[r][comp]); // C[m][t] = d*W + S
          cml[r] = fminf(Cv, prcMin);                             // cmin2 = min(C[m][t], C[m-1][t])
          prcVal = Cv;
          prcMin = Cv;
        }
        // broadcast owner lane's cmin2 chain + last-row C to all lanes
        float cmB[R];
#pragma unroll
        for (int r = 0; r < R; r++) cmB[r] = rdlane(cml[r], owner);
        float clastv = rdlane(prcVal, owner);
        if (lane == owner) clast4[comp] = clastv;

        // stream update: BRANCH-FREE — 4 independent chains in one basic block
#pragma unroll
        for (int k = 0; k < 4; k++) {
          const float w_ = wv[tt][k];
          float cbv = c[tt][k];
#pragma unroll
          for (int r = 0; r < R; r++) {
            float a = fminf(cmB[r], cbv);
            S[r][k] = fmaf(w_, a, S[r][k]);   // w_==0 -> exact no-op (INFF finite)
            cbv = dl[r][k] + a;
          }
          c[tt][k] = (w_ > 0.f) ? cbv : c[tt][k];   // single end-select preserves skip
        }
      }

      // ---- handoff ----
      if (wave < WVS - 1) {
        // intra-block: write slice + crow to LDS; consumer reads after next barrier
#pragma unroll
        for (int tt = 0; tt < BC; tt++) *(f4*)(lsl + tt * Nn) = c[tt];
        if (lane == 2 * j || lane == 2 * j + 1)
          *(f4*)&crow_lds[wave][j & (SLOTS - 1)][(lane & 1) * 4] = clast4;
      } else if (blk < NBLK - 1) {
        // wave 3: payload slice = 8 cbar rows + crow row; drain; in-step flag publish
        if (lane == 2 * j || lane == 2 * j + 1) {
          float* cp = cbarG + (size_t)j * PROW * Nn + BC * Nn + (lane & 1) * 4;
          asm volatile("global_store_dwordx4 %0, %1, off sc0 sc1" :: "v"(cp), "v"(clast4) : "memory");
        }
        llc_store_cbar8(cbarG + (size_t)j * PROW * Nn + 4 * lane, c); // vmcnt(0) covers crow too
        if (lane == 0) llc_store_int(flags + blk * NCHUNK + j, 1);
      } else {
        // final stage: stash C_last into LDS for the fused reduction
        if (lane == 2 * j || lane == 2 * j + 1)
          *(f4*)&crow_fin[j * BC + (lane & 1) * 4] = clast4;
      }
    }
    __syncthreads();
  }

  // ---- fused final reduction (last block only): out = sum_n p_back[N][n] * C_last[n] ----
  if (blk == NBLK - 1) {
    float fw = p[tid] * q[Nn * Nn + tid] / (p[Nn] + EPSF);
    crow_fin[tid] *= fw;
    __syncthreads();
    for (int sft = 128; sft > 0; sft >>= 1) {
      if (tid < sft) crow_fin[tid] += crow_fin[tid + sft];
      __syncthreads();
    }
    if (tid == 0) out[0] = crow_fin[0];
  }
}

extern "C" void kernel_launch(void* const* d_in, const int* in_sizes, int n_in,
                              void* d_out, int out_size, void* d_ws, size_t ws_size,
                              hipStream_t stream) {
  const float* x = (const float*)d_in[0];
  const float* y = (const float*)d_in[1];
  const float* q = (const float*)d_in[2];
  float* ws = (float*)d_ws;
  float* out = (float*)d_out;
  hipLaunchKernelGGL(k_pre,   dim3(Mm + 64 + 2), dim3(256), 0, stream, x, y, q, ws);
  hipLaunchKernelGGL(k_wbuild,dim3(Nn),  dim3(256), 0, stream, ws + OFF_QC, ws + OFF_P,
                     ws + OFF_WT);
  hipLaunchKernelGGL(k_main,  dim3(NBLK), dim3(256), 0, stream, ws + OFF_D, ws + OFF_WT,
                     ws + OFF_CBAR, (int*)(ws + OFF_FLAG), q, ws + OFF_P, out);
}

// Round 20
// 402.315 us; speedup vs baseline: 1.0614x; 1.0614x over previous
//
#include <hip/hip_runtime.h>

typedef float f4 __attribute__((ext_vector_type(4)));

#define Nn 256
#define Mm 512
#define Dd 64
#define EPSF 1e-6f
#define INFF 1e30f
#define BC 8
#define NCHUNK (Nn / BC)   // 32
#define R 16               // rows per wave-stage
#define NBLK 8             // pipeline groups (blocks)
#define WVS 4              // waves per block (256 threads, 1 wave/SIMD -> 512 VGPR cap)
#define SST (NBLK * WVS)   // 32 stages total
#define SLOTS 4            // LDS slice ring depth
#define QSTR 260           // qc row stride (keeps f4 reads 16B-aligned)

// workspace layout (float offsets; all 4-float aligned)
#define OFF_D     0                    // d[m][n]            512*256
#define OFF_QC    131072               // qc[t][n]=q[n][t], stride QSTR (256 rows)
#define OFF_P     197632               // p[257]
#define OFF_WT    197892               // wT[t][n]=w[n][t]   256*256
#define OFF_CBAR  263428               // inter-block Cbar slices 256*256
#define OFF_CROW  328964               // C row handoffs, SST*Nn
#define OFF_FLAG  337156               // flags[blk][chunk], NBLK*NCHUNK ints

// ---------------- LLC-coherent (sc0 sc1) helpers — proven round-2 forms ----------------
__device__ __forceinline__ int llc_load_int(const int* p) {
  int v;
  asm volatile("global_load_dword %0, %1, off sc0 sc1\n\ts_waitcnt vmcnt(0)"
               : "=v"(v) : "v"(p) : "memory");
  return v;
}
__device__ __forceinline__ void llc_store_int(int* p, int v) {
  asm volatile("global_store_dword %0, %1, off sc0 sc1" :: "v"(p), "v"(v) : "memory");
}
// blocking: 8 cbar rows + 2 crow vectors in one round trip
__device__ __forceinline__ void llc_load_cbar10(const float* b0, const float* cp,
                                                f4 c[8], f4& pl, f4& ph) {
  const float* b1 = b0 + 4 * Nn;
  asm volatile(
    "global_load_dwordx4 %0, %10, off sc0 sc1\n\t"
    "global_load_dwordx4 %1, %10, off offset:1024 sc0 sc1\n\t"
    "global_load_dwordx4 %2, %10, off offset:2048 sc0 sc1\n\t"
    "global_load_dwordx4 %3, %10, off offset:3072 sc0 sc1\n\t"
    "global_load_dwordx4 %4, %11, off sc0 sc1\n\t"
    "global_load_dwordx4 %5, %11, off offset:1024 sc0 sc1\n\t"
    "global_load_dwordx4 %6, %11, off offset:2048 sc0 sc1\n\t"
    "global_load_dwordx4 %7, %11, off offset:3072 sc0 sc1\n\t"
    "global_load_dwordx4 %8, %12, off sc0 sc1\n\t"
    "global_load_dwordx4 %9, %12, off offset:16 sc0 sc1\n\t"
    "s_waitcnt vmcnt(0)"
    : "=v"(c[0]), "=v"(c[1]), "=v"(c[2]), "=v"(c[3]),
      "=v"(c[4]), "=v"(c[5]), "=v"(c[6]), "=v"(c[7]),
      "=v"(pl), "=v"(ph)
    : "v"(b0), "v"(b1), "v"(cp)
    : "memory");
}
__device__ __forceinline__ void llc_store_cbar8(float* b0, const f4 c[8]) {
  float* b1 = b0 + 4 * Nn;
  asm volatile(
    "global_store_dwordx4 %8, %0, off sc0 sc1\n\t"
    "global_store_dwordx4 %8, %1, off offset:1024 sc0 sc1\n\t"
    "global_store_dwordx4 %8, %2, off offset:2048 sc0 sc1\n\t"
    "global_store_dwordx4 %8, %3, off offset:3072 sc0 sc1\n\t"
    "global_store_dwordx4 %9, %4, off sc0 sc1\n\t"
    "global_store_dwordx4 %9, %5, off offset:1024 sc0 sc1\n\t"
    "global_store_dwordx4 %9, %6, off offset:2048 sc0 sc1\n\t"
    "global_store_dwordx4 %9, %7, off offset:3072 sc0 sc1\n\t"
    "s_waitcnt vmcnt(0)"
    :: "v"(c[0]), "v"(c[1]), "v"(c[2]), "v"(c[3]),
       "v"(c[4]), "v"(c[5]), "v"(c[6]), "v"(c[7]),
       "v"(b0), "v"(b1)
    : "memory");
}
__device__ __forceinline__ float rdlane(float v, int l) {
  return __int_as_float(__builtin_amdgcn_readlane(__float_as_int(v), l));
}

// ---- fused setup: dist (b<512) | tiled transpose (b<576) | init (b==576) | reach (b==577) ----
__global__ __launch_bounds__(256) void k_pre(const float* __restrict__ x,
                                             const float* __restrict__ y,
                                             const float* __restrict__ q,
                                             float* __restrict__ ws) {
  __shared__ float xs[Dd];
  __shared__ float tile[32][33];
  __shared__ float p[257];
  __shared__ float vsnap[64];
  __shared__ float qtile[64][65];
  const int b = blockIdx.x, t = threadIdx.x;
  if (b < Mm) {
    if (t < Dd) xs[t] = x[b * Dd + t];
    __syncthreads();
    const float4* y4 = (const float4*)(y + t * Dd);
    float acc = 0.f;
#pragma unroll
    for (int k = 0; k < Dd / 4; k++) {
      float4 v = y4[k];
      float a0 = xs[4*k+0] - v.x, a1 = xs[4*k+1] - v.y;
      float a2 = xs[4*k+2] - v.z, a3 = xs[4*k+3] - v.w;
      acc += a0*a0 + a1*a1 + a2*a2 + a3*a3;
    }
    ws[OFF_D + b * Nn + t] = sqrtf(acc);
  } else if (b < Mm + 64) {
    // tiled 32x32 transpose: qc[t][j] = q[j][t], both sides coalesced
    const int tb = b - Mm;
    const int t0 = (tb & 7) * 32;
    const int j0 = (tb >> 3) * 32;
    const int tx = t & 31, ty = t >> 5;   // 32 x 8
#pragma unroll
    for (int dy = 0; dy < 4; dy++)
      tile[ty + 8 * dy][tx] = q[(j0 + ty + 8 * dy) * Nn + t0 + tx];
    __syncthreads();
#pragma unroll
    for (int dy = 0; dy < 4; dy++)
      ws[OFF_QC + (t0 + ty + 8 * dy) * QSTR + j0 + tx] = tile[tx][ty + 8 * dy];
  } else if (b == Mm + 64) {
    ((int*)(ws + OFF_FLAG))[t] = 0;       // NBLK*NCHUNK == 256 flags
  } else {
    // ---- reachability (round-12 verified code; q read directly) ----
    float* p_out = ws + OFF_P;
    p[t] = (t == 0) ? 1.f : 0.f;
    if (t == 0) p[256] = 0.f;
    __syncthreads();
    for (int g = 0; g < 4; g++) {
      int g0 = g * 64;
      for (int z = 0; z < 16; z++) {
        int idx = t + z * 256, l = idx >> 6, k = idx & 63;
        qtile[k][l] = q[(g0 + l) * Nn + g0 + k];
      }
      __syncthreads();
      if (t < 64) {
        float pv = p[g0 + t];
        for (int k = 0; k < 64; k++) {
          float v = __shfl(pv, k, 64);
          if (t == k) vsnap[k] = v;
          pv += v * qtile[k][t];
        }
      }
      __syncthreads();
      float4 qs[16];
      const float4* qrow = (const float4*)(q + t * Nn + g0);
#pragma unroll
      for (int i = 0; i < 16; i++) qs[i] = qrow[i];
      float acc = p[t];
#pragma unroll
      for (int i = 0; i < 16; i++) {
        acc += vsnap[4*i+0] * qs[i].x;
        acc += vsnap[4*i+1] * qs[i].y;
        acc += vsnap[4*i+2] * qs[i].z;
        acc += vsnap[4*i+3] * qs[i].w;
      }
      float acc2 = 0.f;
      if (t == 0) {
        acc2 = p[256];
        const float4* qlast = (const float4*)(q + 256 * Nn + g0);
#pragma unroll
        for (int i = 0; i < 16; i++) {
          float4 v = qlast[i];
          acc2 += vsnap[4*i+0] * v.x + vsnap[4*i+1] * v.y
                + vsnap[4*i+2] * v.z + vsnap[4*i+3] * v.w;
        }
      }
      __syncthreads();
      p[t] = acc;
      if (t == 0) p[256] = acc2;
      __syncthreads();
    }
    p_out[t] = p[t];
    if (t == 0) p_out[256] = p[256];
  }
}

// wT only — no atomics (k_main sums its own columns in a coalesced prologue)
__global__ __launch_bounds__(256) void k_wbuild(const float* __restrict__ qc, const float* __restrict__ p,
                                                float* __restrict__ wT) {
  int t = blockIdx.x, n = threadIdx.x;
  float v = 0.f;
  if (t < n) v = p[t] * qc[t * QSTR + n] / (p[n] + EPSF);
  wT[t * Nn + n] = v;
}

// ---------------- main systolic DP: 8 blocks x 4 waves, round-2 protocol ----------------
// Round-16 verified-best kernel (320 us): branch-free stream update — the 4 independent
// 16-deep column chains share one basic block so the scheduler interleaves them (4-way ILP;
// VGPR 176, 1 wave/SIMD so the 512-cap accommodates it). Safe because INFF=1e30 is FINITE:
// w_==0 gives S += 0*a == S exactly; a single end-select preserves the skip semantics for c.
__global__ __launch_bounds__(256, 1) void k_main(const float* __restrict__ d,
                                                 const float* __restrict__ wT,
                                                 float* __restrict__ cbarG,
                                                 float* __restrict__ crowG,
                                                 int* __restrict__ flags,
                                                 const float* __restrict__ q,
                                                 const float* __restrict__ p,
                                                 float* __restrict__ out) {
  __shared__ __align__(16) float sbuf[SLOTS][BC * Nn];       // 32 KB slice ring
  __shared__ __align__(16) float crow_lds[WVS][SLOTS][BC];   // crow handoffs
  __shared__ __align__(16) float crow_fin[Nn];               // last block: C_last stash

  const int tid  = threadIdx.x;
  const int wave = tid >> 6;         // 0..3: stage within block
  const int lane = tid & 63;         // owns columns 4*lane .. 4*lane+3
  const int blk  = blockIdx.x;
  const int stage = blk * WVS + wave;
  const int m0 = stage * R;

  f4 dl[R], S[R];
#pragma unroll
  for (int r = 0; r < R; r++) {
    dl[r] = *(const f4*)(d + (m0 + r) * Nn + 4 * lane);
    S[r] = (f4){0.f, 0.f, 0.f, 0.f};
  }
  // Wt prologue: column sums of wT (coalesced; wT is zero where t >= n)
  f4 Wt = (f4){0.f, 0.f, 0.f, 0.f};
#pragma unroll 8
  for (int t = 0; t < Nn; t++)
    Wt += *(const f4*)(wT + t * Nn + 4 * lane);

#pragma clang loop unroll(disable)
  for (int s = 0; s < NCHUNK + WVS - 1; s++) {
    const int j = s - wave;
    if (j >= 0 && j < NCHUNK) {
      // wT chunk: plain cached loads (read-only, L2-resident) — issue before any wait
      f4 wv[BC];
#pragma unroll
      for (int tt = 0; tt < BC; tt++)
        wv[tt] = *(const f4*)(wT + (j * BC + tt) * Nn + 4 * lane);

      f4 c[BC], cpl, cph;
      float* lsl = &sbuf[j & (SLOTS - 1)][0] + 4 * lane;

      if (wave == 0) {
        if (blk > 0) {
          const int* fp = flags + (blk - 1) * NCHUNK + j;
          while (llc_load_int(fp) == 0) __builtin_amdgcn_s_sleep(1);
          llc_load_cbar10(cbarG + (size_t)j * BC * Nn + 4 * lane,
                          crowG + (blk - 1) * Nn + j * BC, c, cpl, cph);
        } else {
          cpl = (f4){INFF, INFF, INFF, INFF};
          cph = cpl;
#pragma unroll
          for (int tt = 0; tt < BC; tt++) c[tt] = cpl;
        }
      } else {
        // slice written by wave-1 at step s-1 (barrier-separated)
#pragma unroll
        for (int tt = 0; tt < BC; tt++) c[tt] = *(const f4*)(lsl + tt * Nn);
        const float* cr = &crow_lds[wave - 1][j & (SLOTS - 1)][0];
        cpl = *(const f4*)cr;
        cph = *(const f4*)(cr + 4);
      }

      f4 clast4;
      const bool isJ0 = (j == 0);
#pragma unroll
      for (int tt = 0; tt < BC; tt++) {
        const int owner = 2 * j + (tt >> 2);   // wave-uniform
        const int comp = tt & 3;               // == t & 3 (compile-time)
        const bool isT0 = isJ0 && (tt == 0);

        float up = (tt < 4) ? cpl[comp] : cph[comp];   // upstream C[m0-1][t]
        float prcMin = up;                              // for cmin2
        float prcVal = up;                              // for the t==0 value chain
        if (isT0 && stage == 0) prcVal = 0.f;
        float cml[R];
#pragma unroll
        for (int r = 0; r < R; r++) {
          float Cv;
          if (isT0) Cv = dl[r][0] + prcVal;                       // C[m][0] = d + C[m-1][0]
          else      Cv = fmaf(dl[r][comp], Wt[comp], S[r][comp]); // C[m][t] = d*W + S
          cml[r] = fminf(Cv, prcMin);                             // cmin2 = min(C[m][t], C[m-1][t])
          prcVal = Cv;
          prcMin = Cv;
        }
        // broadcast owner lane's cmin2 chain + last-row C to all lanes
        float cmB[R];
#pragma unroll
        for (int r = 0; r < R; r++) cmB[r] = rdlane(cml[r], owner);
        float clastv = rdlane(prcVal, owner);
        if (lane == owner) clast4[comp] = clastv;

        // stream update: BRANCH-FREE — 4 independent chains in one basic block
#pragma unroll
        for (int k = 0; k < 4; k++) {
          const float w_ = wv[tt][k];
          float cbv = c[tt][k];
#pragma unroll
          for (int r = 0; r < R; r++) {
            float a = fminf(cmB[r], cbv);
            S[r][k] = fmaf(w_, a, S[r][k]);   // w_==0 -> exact no-op (INFF finite)
            cbv = dl[r][k] + a;
          }
          c[tt][k] = (w_ > 0.f) ? cbv : c[tt][k];   // single end-select preserves skip
        }
      }

      // ---- handoff ----
      if (wave < WVS - 1) {
        // intra-block: write slice + crow to LDS; consumer reads after next barrier
#pragma unroll
        for (int tt = 0; tt < BC; tt++) *(f4*)(lsl + tt * Nn) = c[tt];
        if (lane == 2 * j || lane == 2 * j + 1)
          *(f4*)&crow_lds[wave][j & (SLOTS - 1)][(lane & 1) * 4] = clast4;
      } else if (blk < NBLK - 1) {
        // wave 3: inter-block handoff via LLC (in-step publish, round-2 proven)
        if (lane == 2 * j || lane == 2 * j + 1) {
          float* cp = crowG + blk * Nn + j * BC + (lane & 1) * 4;
          asm volatile("global_store_dwordx4 %0, %1, off sc0 sc1" :: "v"(cp), "v"(clast4) : "memory");
        }
        llc_store_cbar8(cbarG + (size_t)j * BC * Nn + 4 * lane, c); // vmcnt(0) covers crow too
        if (lane == 0) llc_store_int(flags + blk * NCHUNK + j, 1);
      } else {
        // final stage: stash C_last into LDS for the fused reduction
        if (lane == 2 * j || lane == 2 * j + 1)
          *(f4*)&crow_fin[j * BC + (lane & 1) * 4] = clast4;
      }
    }
    __syncthreads();
  }

  // ---- fused final reduction (last block only): out = sum_n p_back[N][n] * C_last[n] ----
  if (blk == NBLK - 1) {
    float fw = p[tid] * q[Nn * Nn + tid] / (p[Nn] + EPSF);
    crow_fin[tid] *= fw;
    __syncthreads();
    for (int sft = 128; sft > 0; sft >>= 1) {
      if (tid < sft) crow_fin[tid] += crow_fin[tid + sft];
      __syncthreads();
    }
    if (tid == 0) out[0] = crow_fin[0];
  }
}

extern "C" void kernel_launch(void* const* d_in, const int* in_sizes, int n_in,
                              void* d_out, int out_size, void* d_ws, size_t ws_size,
                              hipStream_t stream) {
  const float* x = (const float*)d_in[0];
  const float* y = (const float*)d_in[1];
  const float* q = (const float*)d_in[2];
  float* ws = (float*)d_ws;
  float* out = (float*)d_out;
  hipLaunchKernelGGL(k_pre,   dim3(Mm + 64 + 2), dim3(256), 0, stream, x, y, q, ws);
  hipLaunchKernelGGL(k_wbuild,dim3(Nn),  dim3(256), 0, stream, ws + OFF_QC, ws + OFF_P,
                     ws + OFF_WT);
  hipLaunchKernelGGL(k_main,  dim3(NBLK), dim3(256), 0, stream, ws + OFF_D, ws + OFF_WT,
                     ws + OFF_CBAR, ws + OFF_CROW, (int*)(ws + OFF_FLAG),
                     q, ws + OFF_P, out);
}